// Round 7
// baseline (269.234 us; speedup 1.0000x reference)
//
#include <hip/hip_runtime.h>
#include <math.h>

#define BB 2
#define TSS 12
#define NN 5000
#define EE 80000
#define NHEAD 4
#define NOUT 16
#define NEMB 64
#define NCCH 64
#define KW 3
#define NHOR 12
#define NBT (BB*TSS)     // 24
#define NEG 0.2f
#define CAP 64           // per-node bucket capacity; Poisson(16) tail ~1e-18
#define BLK 512
#define NPB 8            // nodes per block
#define NGRID 625        // = NN/NPB = EE/128 (both exact)
#define EPB 128          // edges per block in phase B

// workspace layout (4-byte units)
#define OFF_CUR 0        // 5000 ints
#define OFF_BAR 5000     // 1 int (grid-barrier counter)
#define OFF_BKT 5008     // 5000*64 ints

__device__ __forceinline__ float lrelu(float v) { return v >= 0.f ? v : NEG * v; }

__global__ __launch_bounds__(512) void k_zero(int* __restrict__ p) {
    int i = blockIdx.x * 512 + threadIdx.x;
    if (i < 5001) p[i] = 0;
}

// per-block precompute of fused small weights into LDS (968 tasks)
__device__ __forceinline__ void wtask(int tsk,
    const float* __restrict__ Wg, const float* __restrict__ a_src,
    const float* __restrict__ a_dst, const float* __restrict__ bg,
    const float* __restrict__ Wc,
    float* __restrict__ wcwS, float* __restrict__ cbS, float* __restrict__ csS)
{
    if (tsk < 768) {                       // WcW[o][hd][k]
        int o = tsk / 12, r = tsk % 12, hd = r / 3, k = r % 3;
        float s = 0.f;
#pragma unroll
        for (int d = 0; d < NOUT; ++d)
            s += Wg[hd * NOUT + d] * Wc[(o * NEMB + hd * NOUT + d) * KW + k];
        wcwS[tsk] = s;
    } else if (tsk < 960) {                // cb[o][k]
        int q = tsk - 768; int o = q / 3, k = q % 3;
        float s = 0.f;
#pragma unroll
        for (int c = 0; c < NEMB; ++c)
            s += bg[c] * Wc[(o * NEMB + c) * KW + k];
        cbS[q] = s;
    } else if (tsk < 968) {                // cs[0..3], cd[4..7]
        int i = tsk - 960; int h = i & 3;
        const float* av = (i < 4) ? a_src : a_dst;
        float s = 0.f;
#pragma unroll
        for (int d = 0; d < NOUT; ++d) s += Wg[h * NOUT + d] * av[h * NOUT + d];
        csS[i] = s;
    }
}

__global__ __launch_bounds__(BLK, 6) void k_all(
    const float* __restrict__ x, const int* __restrict__ ei,
    const float* __restrict__ Wg, const float* __restrict__ a_src,
    const float* __restrict__ a_dst, const float* __restrict__ bg,
    const float* __restrict__ Wc, const float* __restrict__ bc,
    const float* __restrict__ Wh, const float* __restrict__ bh,
    int* __restrict__ wsI, float* __restrict__ out)
{
    __shared__ float wcwS[768];
    __shared__ float cbS[192];
    __shared__ float csS[8];
    __shared__ int   cntS[NPB];
    __shared__ float sS[NPB][NBT][NHEAD];
    __shared__ float sz[NPB][BB][NCCH];

    int* cur = wsI + OFF_CUR;
    int* bar = wsI + OFF_BAR;
    int* bkt = wsI + OFF_BKT;

    int tid = threadIdx.x;
    int bid = blockIdx.x;
    int node0 = bid * NPB;

    // ---- phase B: scatter this block's 128-edge slice into global buckets ----
    if (tid < EPB) {
        int e = bid * EPB + tid;
        int s = ei[e], d = ei[EE + e];
        int pos = atomicAdd(&cur[d], 1);
        if (pos < CAP) bkt[d * CAP + pos] = s;
    }
    // independent: fused weights into LDS (hides before barrier)
    wtask(tid,       Wg, a_src, a_dst, bg, Wc, wcwS, cbS, csS);
    wtask(tid + BLK, Wg, a_src, a_dst, bg, Wc, wcwS, cbS, csS);

    // ---- manual grid barrier (device scope; all 625 blocks co-resident) ----
    __threadfence();
    __syncthreads();
    if (tid == 0) {
        atomicAdd(bar, 1);
        while (atomicAdd(bar, 0) < NGRID) __builtin_amdgcn_s_sleep(8);
    }
    __syncthreads();
    __threadfence();

    // counts via device-scope RMW (avoid any stale cached read)
    if (tid < NPB) {
        int c = atomicAdd(&cur[node0 + tid], 0);
        cntS[tid] = (c > CAP) ? CAP : c;
    }
    __syncthreads();

    // ---- phase C: segment softmax-aggregate, 8 lanes per (node, bt) ----
    int u = tid >> 6, ul = tid & 63, g = ul >> 3, gl = ul & 7;
    int node = node0 + u;
    int cnt = cntS[u];
    float c0 = csS[0], c1 = csS[1], c2 = csS[2], c3 = csS[3];
    float q0 = csS[4], q1 = csS[5], q2 = csS[6], q3 = csS[7];

    int idxr[8];
#pragma unroll
    for (int i = 0; i < 8; ++i) {
        int e = gl + (i << 3);
        idxr[i] = (e < cnt) ? bkt[node * CAP + e] : 0;
    }

    for (int it = 0; it < 3; ++it) {
        int bt = g + (it << 3);
        const float* xb = x + bt * NN;
        float xd = xb[node];
        float d0 = q0*xd, d1 = q1*xd, d2 = q2*xd, d3 = q3*xd;

        float xsr[8];
        float mx = -INFINITY, mn = INFINITY;
#pragma unroll
        for (int i = 0; i < 8; ++i) {
            int e = gl + (i << 3);
            if (e < cnt) {
                float v = xb[idxr[i]];
                xsr[i] = v;
                mx = fmaxf(mx, v); mn = fminf(mn, v);
            }
        }
#pragma unroll
        for (int m = 1; m < 8; m <<= 1) {
            mx = fmaxf(mx, __shfl_xor(mx, m));
            mn = fminf(mn, __shfl_xor(mn, m));
        }
        // exact per-head max (leaky_relu(affine) monotone in xs)
        float m0 = lrelu((c0 >= 0.f ? c0*mx : c0*mn) + d0);
        float m1 = lrelu((c1 >= 0.f ? c1*mx : c1*mn) + d1);
        float m2 = lrelu((c2 >= 0.f ? c2*mx : c2*mn) + d2);
        float m3 = lrelu((c3 >= 0.f ? c3*mx : c3*mn) + d3);

        float a0=0.f,a1=0.f,a2=0.f,a3=0.f, b0=0.f,b1=0.f,b2=0.f,b3=0.f;
#pragma unroll
        for (int i = 0; i < 8; ++i) {
            int e = gl + (i << 3);
            if (e < cnt) {
                float xs = xsr[i];
                float w0 = __expf(lrelu(c0*xs + d0) - m0); a0 += w0; b0 += w0*xs;
                float w1 = __expf(lrelu(c1*xs + d1) - m1); a1 += w1; b1 += w1*xs;
                float w2 = __expf(lrelu(c2*xs + d2) - m2); a2 += w2; b2 += w2*xs;
                float w3 = __expf(lrelu(c3*xs + d3) - m3); a3 += w3; b3 += w3*xs;
            }
        }
#pragma unroll
        for (int m = 1; m < 8; m <<= 1) {
            a0 += __shfl_xor(a0, m); a1 += __shfl_xor(a1, m);
            a2 += __shfl_xor(a2, m); a3 += __shfl_xor(a3, m);
            b0 += __shfl_xor(b0, m); b1 += __shfl_xor(b1, m);
            b2 += __shfl_xor(b2, m); b3 += __shfl_xor(b3, m);
        }
        if (gl < 4) {
            float av = gl==0 ? a0 : gl==1 ? a1 : gl==2 ? a2 : a3;
            float bv = gl==0 ? b0 : gl==1 ? b1 : gl==2 ? b2 : b3;
            sS[u][bt][gl] = bv / (av + 1e-16f);
        }
    }
    __syncthreads();

    // ---- temporal conv + relu + mean, per output channel o = ul ----
    int o = ul;
    float wcw[NHEAD][KW];
#pragma unroll
    for (int hd = 0; hd < NHEAD; ++hd)
#pragma unroll
        for (int k = 0; k < KW; ++k)
            wcw[hd][k] = wcwS[o * (NHEAD * KW) + hd * KW + k];
    float cbk[KW];
#pragma unroll
    for (int k = 0; k < KW; ++k) cbk[k] = cbS[o * KW + k];
    float bco = bc[o];
#pragma unroll
    for (int b = 0; b < BB; ++b) {
        float acc = 0.f;
#pragma unroll
        for (int t = 0; t < TSS; ++t) {
            float zt = bco;
#pragma unroll
            for (int k = 0; k < KW; ++k) {
                int tau = t + k - 1;
                if (tau >= 0 && tau < TSS) {
                    zt += cbk[k];
#pragma unroll
                    for (int hd = 0; hd < NHEAD; ++hd)
                        zt += sS[u][b * TSS + tau][hd] * wcw[hd][k];
                }
            }
            acc += fmaxf(zt, 0.f);
        }
        sz[u][b][o] = acc * (1.f / 12.f);
    }
    __syncthreads();

    // ---- head linear + output ----
    if (o < NHOR) {
#pragma unroll
        for (int b = 0; b < BB; ++b) {
            float y = bh[o];
#pragma unroll
            for (int c = 0; c < NCCH; ++c) y += sz[u][b][c] * Wh[o * NCCH + c];
            out[(b * NHOR + o) * NN + node] = y;
        }
    }
}

extern "C" void kernel_launch(void* const* d_in, const int* in_sizes, int n_in,
                              void* d_out, int out_size, void* d_ws, size_t ws_size,
                              hipStream_t stream) {
    const float* x     = (const float*)d_in[0];
    const int*   ei    = (const int*)d_in[1];
    const float* Wg    = (const float*)d_in[2];
    const float* a_src = (const float*)d_in[3];
    const float* a_dst = (const float*)d_in[4];
    const float* bg    = (const float*)d_in[5];
    const float* Wc    = (const float*)d_in[6];
    const float* bc    = (const float*)d_in[7];
    const float* Wh    = (const float*)d_in[8];
    const float* bh    = (const float*)d_in[9];
    float* out = (float*)d_out;
    int*   wsI = (int*)d_ws;

    hipLaunchKernelGGL(k_zero, dim3(10), dim3(512), 0, stream, wsI);
    hipLaunchKernelGGL(k_all, dim3(NGRID), dim3(BLK), 0, stream,
                       x, ei, Wg, a_src, a_dst, bg, Wc, bc, Wh, bh, wsI, out);
}

// Round 8
// 54.685 us; speedup vs baseline: 4.9233x; 4.9233x over previous
//
#include <hip/hip_runtime.h>
#include <math.h>

#define BB 2
#define TSS 12
#define NN 5000
#define EE 80000
#define NHEAD 4
#define NOUT 16
#define NEMB 64
#define NCCH 64
#define KW 3
#define NHOR 12
#define NBT (BB*TSS)     // 24
#define NEG 0.2f
#define CAP 64           // per-node bucket capacity; Poisson(16), max deg ~36
#define NPB 8            // nodes per block in segfinal
#define SBLK 512

// workspace layout (4-byte units)
#define OFF_CUR  0       // 5000 ints
#define OFF_CS   5008    // 4 floats
#define OFF_CD   5012    // 4
#define OFF_WCW  5016    // 768  [o*12 + hd*3 + k]
#define OFF_CB   5784    // 192  [o*3 + k]
#define OFF_BKT  6000    // 5000*64 ushorts = 160000 ints

__device__ __forceinline__ float lrelu(float v) { return v >= 0.f ? v : NEG * v; }

__global__ __launch_bounds__(256) void k_zero(int* __restrict__ p) {
    int i = blockIdx.x * 256 + threadIdx.x;
    if (i < NN) p[i] = 0;
}

// fused small-weight precompute (968 tasks) -> global ws
__device__ __forceinline__ void wtask(int tsk, float* __restrict__ wsF,
    const float* __restrict__ Wg, const float* __restrict__ a_src,
    const float* __restrict__ a_dst, const float* __restrict__ bg,
    const float* __restrict__ Wc)
{
    if (tsk < 768) {                       // WcW[o][hd][k]
        int o = tsk / 12, r = tsk % 12, hd = r / 3, k = r % 3;
        float s = 0.f;
#pragma unroll
        for (int d = 0; d < NOUT; ++d)
            s += Wg[hd * NOUT + d] * Wc[(o * NEMB + hd * NOUT + d) * KW + k];
        wsF[OFF_WCW + tsk] = s;
    } else if (tsk < 960) {                // cb[o][k]
        int q = tsk - 768; int o = q / 3, k = q % 3;
        float s = 0.f;
#pragma unroll
        for (int c = 0; c < NEMB; ++c)
            s += bg[c] * Wc[(o * NEMB + c) * KW + k];
        wsF[OFF_CB + q] = s;
    } else if (tsk < 968) {                // cs[0..3], cd[4..7]
        int i = tsk - 960; int h = i & 3;
        const float* av = (i < 4) ? a_src : a_dst;
        float s = 0.f;
#pragma unroll
        for (int d = 0; d < NOUT; ++d) s += Wg[h * NOUT + d] * av[h * NOUT + d];
        wsF[(i < 4 ? OFF_CS : OFF_CD) + h] = s;
    }
}

// K1: bucket scatter (ushort src) + block 0 computes fused weights
__global__ __launch_bounds__(256) void k_bucket(
    const int* __restrict__ ei, int* __restrict__ cur,
    unsigned short* __restrict__ bkt, float* __restrict__ wsF,
    const float* __restrict__ Wg, const float* __restrict__ a_src,
    const float* __restrict__ a_dst, const float* __restrict__ bg,
    const float* __restrict__ Wc)
{
    int e = blockIdx.x * 256 + threadIdx.x;
    if (e < EE) {
        int s = ei[e], d = ei[EE + e];
        int pos = atomicAdd(&cur[d], 1);
        if (pos < CAP) bkt[d * CAP + pos] = (unsigned short)s;
    }
    if (blockIdx.x == 0) {
        int t = threadIdx.x;
        wtask(t,       wsF, Wg, a_src, a_dst, bg, Wc);
        wtask(t + 256, wsF, Wg, a_src, a_dst, bg, Wc);
        wtask(t + 512, wsF, Wg, a_src, a_dst, bg, Wc);
        wtask(t + 768, wsF, Wg, a_src, a_dst, bg, Wc);
    }
}

// K2: seg-softmax-aggregate + conv + head linear.
// 8 lanes per (node,bt): lane = head(0..3) + 4*half. One shfl_xor(4) per value.
__global__ __launch_bounds__(SBLK) void k_segfinal(
    const float* __restrict__ x, const int* __restrict__ cur,
    const unsigned short* __restrict__ bkt, const float* __restrict__ wsF,
    const float* __restrict__ bc, const float* __restrict__ Wh,
    const float* __restrict__ bh, float* __restrict__ out)
{
    int tid = threadIdx.x;
    int u = tid >> 6, ul = tid & 63, grp = ul >> 3, gl = ul & 7;
    int h = gl & 3, half = gl >> 2;
    int node = blockIdx.x * NPB + u;

    __shared__ float sS[NPB][NBT][NHEAD];
    __shared__ float sz[NPB][BB][NCCH];

    int cnt = cur[node]; if (cnt > CAP) cnt = CAP;
    int hc = (cnt + 1) >> 1;
    int base = half ? hc : 0;
    int len = half ? cnt - hc : hc;        // <= 32

    // bt-invariant: bucket indices into regs (16 static slots + rare tail)
    const unsigned short* brow = bkt + node * CAP + base;
    int idxr[16];
#pragma unroll
    for (int j = 0; j < 16; ++j) idxr[j] = (j < len) ? (int)brow[j] : 0;

    float ch = wsF[OFF_CS + h];
    float qh = wsF[OFF_CD + h];

    for (int it = 0; it < 3; ++it) {
        int bt = grp + (it << 3);
        const float* xb = x + bt * NN;
        float xd = xb[node];
        float dh = qh * xd;

        float xsr[16];
        float mx = -INFINITY, mn = INFINITY;
#pragma unroll
        for (int j = 0; j < 16; ++j) {
            if (j < len) {
                float v = xb[idxr[j]];
                xsr[j] = v;
                mx = fmaxf(mx, v); mn = fminf(mn, v);
            }
        }
        for (int j = 16; j < len; ++j) {    // rare tail (deg > 32)
            float v = xb[brow[j]];
            mx = fmaxf(mx, v); mn = fminf(mn, v);
        }
        mx = fmaxf(mx, __shfl_xor(mx, 4));
        mn = fminf(mn, __shfl_xor(mn, 4));
        // exact per-head max (leaky_relu(affine) monotone in xs)
        float m = lrelu((ch >= 0.f ? ch * mx : ch * mn) + dh);

        float a = 0.f, b = 0.f;
#pragma unroll
        for (int j = 0; j < 16; ++j) {
            if (j < len) {
                float xs = xsr[j];
                float w = __expf(lrelu(ch * xs + dh) - m);
                a += w; b += w * xs;
            }
        }
        for (int j = 16; j < len; ++j) {
            float xs = xb[brow[j]];
            float w = __expf(lrelu(ch * xs + dh) - m);
            a += w; b += w * xs;
        }
        a += __shfl_xor(a, 4);
        b += __shfl_xor(b, 4);
        if (half == 0) sS[u][bt][h] = b / (a + 1e-16f);
    }
    __syncthreads();

    // ---- temporal conv + relu + mean, per output channel o = ul ----
    int o = ul;
    float wcw[NHEAD][KW];
#pragma unroll
    for (int hd = 0; hd < NHEAD; ++hd)
#pragma unroll
        for (int k = 0; k < KW; ++k)
            wcw[hd][k] = wsF[OFF_WCW + o * (NHEAD * KW) + hd * KW + k];
    float cbk[KW];
#pragma unroll
    for (int k = 0; k < KW; ++k) cbk[k] = wsF[OFF_CB + o * KW + k];
    float bco = bc[o];
#pragma unroll
    for (int b = 0; b < BB; ++b) {
        float acc = 0.f;
#pragma unroll
        for (int t = 0; t < TSS; ++t) {
            float zt = bco;
#pragma unroll
            for (int k = 0; k < KW; ++k) {
                int tau = t + k - 1;
                if (tau >= 0 && tau < TSS) {
                    zt += cbk[k];
#pragma unroll
                    for (int hd = 0; hd < NHEAD; ++hd)
                        zt += sS[u][b * TSS + tau][hd] * wcw[hd][k];
                }
            }
            acc += fmaxf(zt, 0.f);
        }
        sz[u][b][o] = acc * (1.f / 12.f);
    }
    __syncthreads();

    if (o < NHOR) {
#pragma unroll
        for (int b = 0; b < BB; ++b) {
            float y = bh[o];
#pragma unroll
            for (int c = 0; c < NCCH; ++c) y += sz[u][b][c] * Wh[o * NCCH + c];
            out[(b * NHOR + o) * NN + node] = y;
        }
    }
}

extern "C" void kernel_launch(void* const* d_in, const int* in_sizes, int n_in,
                              void* d_out, int out_size, void* d_ws, size_t ws_size,
                              hipStream_t stream) {
    const float* x     = (const float*)d_in[0];
    const int*   ei    = (const int*)d_in[1];
    const float* Wg    = (const float*)d_in[2];
    const float* a_src = (const float*)d_in[3];
    const float* a_dst = (const float*)d_in[4];
    const float* bg    = (const float*)d_in[5];
    const float* Wc    = (const float*)d_in[6];
    const float* bc    = (const float*)d_in[7];
    const float* Wh    = (const float*)d_in[8];
    const float* bh    = (const float*)d_in[9];
    float* out = (float*)d_out;
    int*   wsI = (int*)d_ws;
    float* wsF = (float*)d_ws;
    unsigned short* bkt = (unsigned short*)(wsI + OFF_BKT);

    hipLaunchKernelGGL(k_zero, dim3(20), dim3(256), 0, stream, wsI + OFF_CUR);
    hipLaunchKernelGGL(k_bucket, dim3((EE + 255) / 256), dim3(256), 0, stream,
                       ei, wsI + OFF_CUR, bkt, wsF, Wg, a_src, a_dst, bg, Wc);
    hipLaunchKernelGGL(k_segfinal, dim3(NN / NPB), dim3(SBLK), 0, stream,
                       x, wsI + OFF_CUR, bkt, wsF, bc, Wh, bh, out);
}

// Round 9
// 46.488 us; speedup vs baseline: 5.7915x; 1.1763x over previous
//
#include <hip/hip_runtime.h>
#include <math.h>

#define BB 2
#define TSS 12
#define NN 5000
#define EE 80000
#define NHEAD 4
#define NOUT 16
#define NEMB 64
#define NCCH 64
#define KW 3
#define NHOR 12
#define NBT (BB*TSS)     // 24
#define NEG 0.2f
#define CAP 64           // per-node bucket capacity; Poisson(16), max deg ~36
#define NPB 4            // nodes per block (1 wave per node)
#define XTS 32           // padded row stride of xT (floats)

// workspace layout (4-byte units)
#define OFF_CUR  0       // 5000 ints
#define OFF_CS   5008    // 4 floats
#define OFF_CD   5012    // 4
#define OFF_WCW  5016    // 768  [o*12 + hd*3 + k]
#define OFF_CB   5784    // 192  [o*3 + k]
#define OFF_XT   6000    // 5000*32 floats = 160000
#define OFF_BKT  166000  // 5000*64 ints = 320000

#define SCAT_BLKS 313    // ceil(80000/256)
#define TR_TASKS  30000  // 5000 nodes * 6 float4-quads
#define TR_BLKS   118    // ceil(30000/256)

__device__ __forceinline__ float lrelu(float v) { return v >= 0.f ? v : NEG * v; }

// fused small-weight precompute (968 tasks) -> global ws
__device__ __forceinline__ void wtask(int tsk, float* __restrict__ wsF,
    const float* __restrict__ Wg, const float* __restrict__ a_src,
    const float* __restrict__ a_dst, const float* __restrict__ bg,
    const float* __restrict__ Wc)
{
    if (tsk < 768) {                       // WcW[o][hd][k]
        int o = tsk / 12, r = tsk % 12, hd = r / 3, k = r % 3;
        float s = 0.f;
#pragma unroll
        for (int d = 0; d < NOUT; ++d)
            s += Wg[hd * NOUT + d] * Wc[(o * NEMB + hd * NOUT + d) * KW + k];
        wsF[OFF_WCW + tsk] = s;
    } else if (tsk < 960) {                // cb[o][k]
        int q = tsk - 768; int o = q / 3, k = q % 3;
        float s = 0.f;
#pragma unroll
        for (int c = 0; c < NEMB; ++c)
            s += bg[c] * Wc[(o * NEMB + c) * KW + k];
        wsF[OFF_CB + q] = s;
    } else if (tsk < 968) {                // cs[0..3], cd[4..7]
        int i = tsk - 960; int h = i & 3;
        const float* av = (i < 4) ? a_src : a_dst;
        float s = 0.f;
#pragma unroll
        for (int d = 0; d < NOUT; ++d) s += Wg[h * NOUT + d] * av[h * NOUT + d];
        wsF[(i < 4 ? OFF_CS : OFF_CD) + h] = s;
    }
}

// K1: bucket scatter + x transpose + (block 0) fused-weight precompute
__global__ __launch_bounds__(256) void k_bucket(
    const float* __restrict__ x, const int* __restrict__ ei,
    int* __restrict__ cur, int* __restrict__ bkt,
    float* __restrict__ wsF,
    const float* __restrict__ Wg, const float* __restrict__ a_src,
    const float* __restrict__ a_dst, const float* __restrict__ bg,
    const float* __restrict__ Wc)
{
    int bid = blockIdx.x, tid = threadIdx.x;
    if (bid < SCAT_BLKS) {
        int e = bid * 256 + tid;
        if (e < EE) {
            int s = ei[e], d = ei[EE + e];
            int pos = atomicAdd(&cur[d], 1);
            if (pos < CAP) bkt[d * CAP + pos] = s;
        }
        if (bid == 0) {
            wtask(tid,       wsF, Wg, a_src, a_dst, bg, Wc);
            wtask(tid + 256, wsF, Wg, a_src, a_dst, bg, Wc);
            wtask(tid + 512, wsF, Wg, a_src, a_dst, bg, Wc);
            wtask(tid + 768, wsF, Wg, a_src, a_dst, bg, Wc);
        }
    } else {
        int idx = (bid - SCAT_BLKS) * 256 + tid;
        if (idx < TR_TASKS) {
            int n = idx / 6, q = idx % 6;
            float4 v;
            v.x = x[(4 * q + 0) * NN + n];
            v.y = x[(4 * q + 1) * NN + n];
            v.z = x[(4 * q + 2) * NN + n];
            v.w = x[(4 * q + 3) * NN + n];
            ((float4*)(wsF + OFF_XT))[n * (XTS / 4) + q] = v;
        }
    }
}

// K2: seg-softmax-aggregate (no max subtraction; shift-invariant) + conv + head linear.
// 1 wave per node; 8 groups of 8 lanes; group g handles bt {3g, 3g+1, 3g+2}.
__global__ __launch_bounds__(256) void k_segfinal(
    const int* __restrict__ cur, const int* __restrict__ bkt,
    const float* __restrict__ wsF,
    const float* __restrict__ bc, const float* __restrict__ Wh,
    const float* __restrict__ bh, float* __restrict__ out)
{
    int tid = threadIdx.x;
    int u = tid >> 6, ul = tid & 63, g = ul >> 3, gl = ul & 7;
    int node = blockIdx.x * NPB + u;
    int bt0 = 3 * g;

    __shared__ float sS[NPB][NBT][NHEAD];
    __shared__ float sz[NPB][BB][NCCH];

    const float* xT = wsF + OFF_XT;
    int cnt = cur[node]; if (cnt > CAP) cnt = CAP;
    const int* brow = bkt + node * CAP;

    int idxr[8];
#pragma unroll
    for (int i = 0; i < 8; ++i) {
        int e = gl + (i << 3);
        idxr[i] = (e < cnt) ? brow[e] : 0;
    }

    // gather all 3 bt x-values per edge slot (12 contiguous bytes each)
    float xsr[3][8];
#pragma unroll
    for (int i = 0; i < 8; ++i) {
        int e = gl + (i << 3);
        if (e < cnt) {
            const float* r = xT + idxr[i] * XTS + bt0;
            xsr[0][i] = r[0]; xsr[1][i] = r[1]; xsr[2][i] = r[2];
        }
    }
    float xdt[3];
    {
        const float* r = xT + node * XTS + bt0;
        xdt[0] = r[0]; xdt[1] = r[1]; xdt[2] = r[2];
    }

    float cc[4], qq[4];
#pragma unroll
    for (int h = 0; h < 4; ++h) { cc[h] = wsF[OFF_CS + h]; qq[h] = wsF[OFF_CD + h]; }

#pragma unroll
    for (int t = 0; t < 3; ++t) {
#pragma unroll
        for (int h = 0; h < 4; ++h) {
            float dh = qq[h] * xdt[t];
            float a = 0.f, b = 0.f;
#pragma unroll
            for (int i = 0; i < 8; ++i) {
                int e = gl + (i << 3);
                if (e < cnt) {
                    float xs = xsr[t][i];
                    float w = __expf(lrelu(cc[h] * xs + dh));
                    a += w; b += w * xs;
                }
            }
            a += __shfl_xor(a, 1); a += __shfl_xor(a, 2); a += __shfl_xor(a, 4);
            b += __shfl_xor(b, 1); b += __shfl_xor(b, 2); b += __shfl_xor(b, 4);
            if (gl == 0) sS[u][bt0 + t][h] = b / (a + 1e-16f);
        }
    }
    __syncthreads();

    // ---- temporal conv + relu + mean, per output channel o = ul ----
    int o = ul;
    float wcw[NHEAD][KW];
#pragma unroll
    for (int hd = 0; hd < NHEAD; ++hd)
#pragma unroll
        for (int k = 0; k < KW; ++k)
            wcw[hd][k] = wsF[OFF_WCW + o * (NHEAD * KW) + hd * KW + k];
    float cbk[KW];
#pragma unroll
    for (int k = 0; k < KW; ++k) cbk[k] = wsF[OFF_CB + o * KW + k];
    float bco = bc[o];
#pragma unroll
    for (int b = 0; b < BB; ++b) {
        float acc = 0.f;
#pragma unroll
        for (int t = 0; t < TSS; ++t) {
            float zt = bco;
#pragma unroll
            for (int k = 0; k < KW; ++k) {
                int tau = t + k - 1;
                if (tau >= 0 && tau < TSS) {
                    zt += cbk[k];
#pragma unroll
                    for (int hd = 0; hd < NHEAD; ++hd)
                        zt += sS[u][b * TSS + tau][hd] * wcw[hd][k];
                }
            }
            acc += fmaxf(zt, 0.f);
        }
        sz[u][b][o] = acc * (1.f / 12.f);
    }
    __syncthreads();

    if (o < NHOR) {
#pragma unroll
        for (int b = 0; b < BB; ++b) {
            float y = bh[o];
#pragma unroll
            for (int c = 0; c < NCCH; ++c) y += sz[u][b][c] * Wh[o * NCCH + c];
            out[(b * NHOR + o) * NN + node] = y;
        }
    }
}

extern "C" void kernel_launch(void* const* d_in, const int* in_sizes, int n_in,
                              void* d_out, int out_size, void* d_ws, size_t ws_size,
                              hipStream_t stream) {
    const float* x     = (const float*)d_in[0];
    const int*   ei    = (const int*)d_in[1];
    const float* Wg    = (const float*)d_in[2];
    const float* a_src = (const float*)d_in[3];
    const float* a_dst = (const float*)d_in[4];
    const float* bg    = (const float*)d_in[5];
    const float* Wc    = (const float*)d_in[6];
    const float* bc    = (const float*)d_in[7];
    const float* Wh    = (const float*)d_in[8];
    const float* bh    = (const float*)d_in[9];
    float* out = (float*)d_out;
    int*   wsI = (int*)d_ws;
    float* wsF = (float*)d_ws;

    hipMemsetAsync(wsI + OFF_CUR, 0, NN * sizeof(int), stream);
    hipLaunchKernelGGL(k_bucket, dim3(SCAT_BLKS + TR_BLKS), dim3(256), 0, stream,
                       x, ei, wsI + OFF_CUR, wsI + OFF_BKT, wsF,
                       Wg, a_src, a_dst, bg, Wc);
    hipLaunchKernelGGL(k_segfinal, dim3(NN / NPB), dim3(256), 0, stream,
                       wsI + OFF_CUR, wsI + OFF_BKT, wsF, bc, Wh, bh, out);
}

// Round 10
// 46.372 us; speedup vs baseline: 5.8059x; 1.0025x over previous
//
#include <hip/hip_runtime.h>
#include <math.h>

#define BB 2
#define TSS 12
#define NN 5000
#define EE 80000
#define NHEAD 4
#define NOUT 16
#define NEMB 64
#define NCCH 64
#define KW 3
#define NHOR 12
#define NBT (BB*TSS)     // 24
#define NEG 0.2f
#define CAP 64           // per-node bucket capacity; Poisson(16), max deg ~36
#define NPB 4            // nodes per block (1 wave per node)
#define XTS 32           // padded row stride of xT (floats)

// workspace layout (4-byte units)
#define OFF_CUR  0       // 5000 ints
#define OFF_CS   5008    // 4 floats
#define OFF_CD   5012    // 4
#define OFF_WCW  5016    // 768  [o*12 + hd*3 + k]
#define OFF_CB   5784    // 192  [o*3 + k]
#define OFF_XT   6000    // 5000*32 floats = 160000
#define OFF_BKT  166000  // 5000*64 ints = 320000

#define SCAT_BLKS 313    // ceil(80000/256)
#define TR_TASKS  30000  // 5000 nodes * 6 float4-quads
#define TR_BLKS   118    // ceil(30000/256)

__device__ __forceinline__ float lrelu(float v) { return v >= 0.f ? v : NEG * v; }

__global__ __launch_bounds__(256) void k_zero(int* __restrict__ p) {
    int i = blockIdx.x * 256 + threadIdx.x;
    if (i < NN) p[i] = 0;
}

// fused small-weight precompute (968 tasks) -> global ws
__device__ __forceinline__ void wtask(int tsk, float* __restrict__ wsF,
    const float* __restrict__ Wg, const float* __restrict__ a_src,
    const float* __restrict__ a_dst, const float* __restrict__ bg,
    const float* __restrict__ Wc)
{
    if (tsk < 768) {                       // WcW[o][hd][k]
        int o = tsk / 12, r = tsk % 12, hd = r / 3, k = r % 3;
        float s = 0.f;
#pragma unroll
        for (int d = 0; d < NOUT; ++d)
            s += Wg[hd * NOUT + d] * Wc[(o * NEMB + hd * NOUT + d) * KW + k];
        wsF[OFF_WCW + tsk] = s;
    } else if (tsk < 960) {                // cb[o][k]
        int q = tsk - 768; int o = q / 3, k = q % 3;
        float s = 0.f;
#pragma unroll
        for (int c = 0; c < NEMB; ++c)
            s += bg[c] * Wc[(o * NEMB + c) * KW + k];
        wsF[OFF_CB + q] = s;
    } else if (tsk < 968) {                // cs[0..3], cd[4..7]
        int i = tsk - 960; int h = i & 3;
        const float* av = (i < 4) ? a_src : a_dst;
        float s = 0.f;
#pragma unroll
        for (int d = 0; d < NOUT; ++d) s += Wg[h * NOUT + d] * av[h * NOUT + d];
        wsF[(i < 4 ? OFF_CS : OFF_CD) + h] = s;
    }
}

// K1: bucket scatter + x transpose + (block 0) fused-weight precompute
__global__ __launch_bounds__(256) void k_bucket(
    const float* __restrict__ x, const int* __restrict__ ei,
    int* __restrict__ cur, int* __restrict__ bkt,
    float* __restrict__ wsF,
    const float* __restrict__ Wg, const float* __restrict__ a_src,
    const float* __restrict__ a_dst, const float* __restrict__ bg,
    const float* __restrict__ Wc)
{
    int bid = blockIdx.x, tid = threadIdx.x;
    if (bid < SCAT_BLKS) {
        int e = bid * 256 + tid;
        if (e < EE) {
            int s = ei[e], d = ei[EE + e];
            int pos = atomicAdd(&cur[d], 1);
            if (pos < CAP) bkt[d * CAP + pos] = s;
        }
        if (bid == 0) {
            wtask(tid,       wsF, Wg, a_src, a_dst, bg, Wc);
            wtask(tid + 256, wsF, Wg, a_src, a_dst, bg, Wc);
            wtask(tid + 512, wsF, Wg, a_src, a_dst, bg, Wc);
            wtask(tid + 768, wsF, Wg, a_src, a_dst, bg, Wc);
        }
    } else {
        int idx = (bid - SCAT_BLKS) * 256 + tid;
        if (idx < TR_TASKS) {
            int n = idx / 6, q = idx % 6;
            float4 v;
            v.x = x[(4 * q + 0) * NN + n];
            v.y = x[(4 * q + 1) * NN + n];
            v.z = x[(4 * q + 2) * NN + n];
            v.w = x[(4 * q + 3) * NN + n];
            ((float4*)(wsF + OFF_XT))[n * (XTS / 4) + q] = v;
        }
    }
}

// K2: seg-softmax-aggregate (no max subtraction; shift-invariant) + conv + head linear.
// 1 wave per node; 8 groups of 8 lanes; group g handles bt {3g, 3g+1, 3g+2}.
__global__ __launch_bounds__(256) void k_segfinal(
    const int* __restrict__ cur, const int* __restrict__ bkt,
    const float* __restrict__ wsF,
    const float* __restrict__ bc, const float* __restrict__ Wh,
    const float* __restrict__ bh, float* __restrict__ out)
{
    int tid = threadIdx.x;
    int u = tid >> 6, ul = tid & 63, g = ul >> 3, gl = ul & 7;
    int node = blockIdx.x * NPB + u;
    int bt0 = 3 * g;

    __shared__ float sS[NPB][NBT][NHEAD];
    __shared__ float sz[NPB][BB][NCCH];

    const float* xT = wsF + OFF_XT;
    int cnt = cur[node]; if (cnt > CAP) cnt = CAP;
    const int* brow = bkt + node * CAP;

    int idxr[8];
#pragma unroll
    for (int i = 0; i < 8; ++i) {
        int e = gl + (i << 3);
        idxr[i] = (e < cnt) ? brow[e] : 0;
    }

    // gather all 3 bt x-values per edge slot (12 contiguous bytes each)
    float xsr[3][8];
#pragma unroll
    for (int i = 0; i < 8; ++i) {
        int e = gl + (i << 3);
        if (e < cnt) {
            const float* r = xT + idxr[i] * XTS + bt0;
            xsr[0][i] = r[0]; xsr[1][i] = r[1]; xsr[2][i] = r[2];
        }
    }
    float xdt[3];
    {
        const float* r = xT + node * XTS + bt0;
        xdt[0] = r[0]; xdt[1] = r[1]; xdt[2] = r[2];
    }

    float cc[4], qq[4];
#pragma unroll
    for (int h = 0; h < 4; ++h) { cc[h] = wsF[OFF_CS + h]; qq[h] = wsF[OFF_CD + h]; }

#pragma unroll
    for (int t = 0; t < 3; ++t) {
#pragma unroll
        for (int h = 0; h < 4; ++h) {
            float dh = qq[h] * xdt[t];
            float a = 0.f, b = 0.f;
#pragma unroll
            for (int i = 0; i < 8; ++i) {
                int e = gl + (i << 3);
                if (e < cnt) {
                    float xs = xsr[t][i];
                    float w = __expf(lrelu(cc[h] * xs + dh));
                    a += w; b += w * xs;
                }
            }
            a += __shfl_xor(a, 1); a += __shfl_xor(a, 2); a += __shfl_xor(a, 4);
            b += __shfl_xor(b, 1); b += __shfl_xor(b, 2); b += __shfl_xor(b, 4);
            if (gl == 0) sS[u][bt0 + t][h] = b / (a + 1e-16f);
        }
    }
    __syncthreads();

    // ---- temporal conv + relu + mean, per output channel o = ul ----
    int o = ul;
    float wcw[NHEAD][KW];
#pragma unroll
    for (int hd = 0; hd < NHEAD; ++hd)
#pragma unroll
        for (int k = 0; k < KW; ++k)
            wcw[hd][k] = wsF[OFF_WCW + o * (NHEAD * KW) + hd * KW + k];
    float cbk[KW];
#pragma unroll
    for (int k = 0; k < KW; ++k) cbk[k] = wsF[OFF_CB + o * KW + k];
    float bco = bc[o];
#pragma unroll
    for (int b = 0; b < BB; ++b) {
        float acc = 0.f;
#pragma unroll
        for (int t = 0; t < TSS; ++t) {
            float zt = bco;
#pragma unroll
            for (int k = 0; k < KW; ++k) {
                int tau = t + k - 1;
                if (tau >= 0 && tau < TSS) {
                    zt += cbk[k];
#pragma unroll
                    for (int hd = 0; hd < NHEAD; ++hd)
                        zt += sS[u][b * TSS + tau][hd] * wcw[hd][k];
                }
            }
            acc += fmaxf(zt, 0.f);
        }
        sz[u][b][o] = acc * (1.f / 12.f);
    }
    __syncthreads();

    if (o < NHOR) {
#pragma unroll
        for (int b = 0; b < BB; ++b) {
            float y = bh[o];
#pragma unroll
            for (int c = 0; c < NCCH; ++c) y += sz[u][b][c] * Wh[o * NCCH + c];
            out[(b * NHOR + o) * NN + node] = y;
        }
    }
}

extern "C" void kernel_launch(void* const* d_in, const int* in_sizes, int n_in,
                              void* d_out, int out_size, void* d_ws, size_t ws_size,
                              hipStream_t stream) {
    const float* x     = (const float*)d_in[0];
    const int*   ei    = (const int*)d_in[1];
    const float* Wg    = (const float*)d_in[2];
    const float* a_src = (const float*)d_in[3];
    const float* a_dst = (const float*)d_in[4];
    const float* bg    = (const float*)d_in[5];
    const float* Wc    = (const float*)d_in[6];
    const float* bc    = (const float*)d_in[7];
    const float* Wh    = (const float*)d_in[8];
    const float* bh    = (const float*)d_in[9];
    float* out = (float*)d_out;
    int*   wsI = (int*)d_ws;
    float* wsF = (float*)d_ws;

    hipLaunchKernelGGL(k_zero, dim3(20), dim3(256), 0, stream, wsI + OFF_CUR);
    hipLaunchKernelGGL(k_bucket, dim3(SCAT_BLKS + TR_BLKS), dim3(256), 0, stream,
                       x, ei, wsI + OFF_CUR, wsI + OFF_BKT, wsF,
                       Wg, a_src, a_dst, bg, Wc);
    hipLaunchKernelGGL(k_segfinal, dim3(NN / NPB), dim3(256), 0, stream,
                       wsI + OFF_CUR, wsI + OFF_BKT, wsF, bc, Wh, bh, out);
}

// Round 11
// 39.099 us; speedup vs baseline: 6.8860x; 1.1860x over previous
//
#include <hip/hip_runtime.h>
#include <math.h>

#define BB 2
#define TSS 12
#define NN 5000
#define EE 80000
#define NHEAD 4
#define NOUT 16
#define NEMB 64
#define NCCH 64
#define KW 3
#define NHOR 12
#define NBT (BB*TSS)     // 24
#define NEG 0.2f
#define CAP 64           // per-node bucket capacity (8 lanes x 8 slots)
#define NPB 4            // nodes per block (1 wave per node)
#define XTS 32           // padded row stride of xT (floats)

// workspace layout (4-byte units)
#define OFF_CUR  0       // 5000 ints
#define OFF_CS   5008    // 4 floats
#define OFF_CD   5012    // 4
#define OFF_WCW  5016    // 768  [o*12 + hd*3 + k]
#define OFF_CB   5784    // 192  [o*3 + k]
#define OFF_XT   6000    // 5000*32 floats = 160000
#define OFF_BKT  166000  // 5000*64 ushorts = 160000 ints equiv (80000 ints)

#define TRB 79           // transpose blocks (79*64 = 5056 >= 5000)
#define WTB 4            // wtask blocks

__device__ __forceinline__ float lrelu(float v) { return v >= 0.f ? v : NEG * v; }

// fused small-weight precompute (968 tasks) -> global ws
__device__ __forceinline__ void wtask(int tsk, float* __restrict__ wsF,
    const float* __restrict__ Wg, const float* __restrict__ a_src,
    const float* __restrict__ a_dst, const float* __restrict__ bg,
    const float* __restrict__ Wc)
{
    if (tsk < 768) {                       // WcW[o][hd][k]
        int o = tsk / 12, r = tsk % 12, hd = r / 3, k = r % 3;
        float s = 0.f;
#pragma unroll
        for (int d = 0; d < NOUT; ++d)
            s += Wg[hd * NOUT + d] * Wc[(o * NEMB + hd * NOUT + d) * KW + k];
        wsF[OFF_WCW + tsk] = s;
    } else if (tsk < 960) {                // cb[o][k]
        int q = tsk - 768; int o = q / 3, k = q % 3;
        float s = 0.f;
#pragma unroll
        for (int c = 0; c < NEMB; ++c)
            s += bg[c] * Wc[(o * NEMB + c) * KW + k];
        wsF[OFF_CB + q] = s;
    } else if (tsk < 968) {                // cs[0..3], cd[4..7]
        int i = tsk - 960; int h = i & 3;
        const float* av = (i < 4) ? a_src : a_dst;
        float s = 0.f;
#pragma unroll
        for (int d = 0; d < NOUT; ++d) s += Wg[h * NOUT + d] * av[h * NOUT + d];
        wsF[(i < 4 ? OFF_CS : OFF_CD) + h] = s;
    }
}

// D1: zero cursors + coalesced tiled transpose x -> xT + fused weights
__global__ __launch_bounds__(256) void k_pre(
    const float* __restrict__ x, float* __restrict__ wsF, int* __restrict__ cur,
    const float* __restrict__ Wg, const float* __restrict__ a_src,
    const float* __restrict__ a_dst, const float* __restrict__ bg,
    const float* __restrict__ Wc)
{
    int bid = blockIdx.x, tid = threadIdx.x;
    if (bid < TRB) {
        __shared__ float tile[64][NBT + 1];
        int n0 = bid * 64;
        if (tid < 64 && n0 + tid < NN) cur[n0 + tid] = 0;
        // load: 24 rows x 64 cols, coalesced along n
#pragma unroll
        for (int j = 0; j < 6; ++j) {
            int idx = tid + j * 256;             // 0..1535
            int row = idx >> 6, col = idx & 63;  // row=bt, col=n-n0
            if (n0 + col < NN) tile[col][row] = x[row * NN + n0 + col];
        }
        __syncthreads();
        // store: xT[n][bt], contiguous in bt
#pragma unroll
        for (int j = 0; j < 6; ++j) {
            int idx = tid + j * 256;             // 0..1535
            int nn = idx / NBT, bt = idx % NBT;
            if (n0 + nn < NN) wsF[OFF_XT + (n0 + nn) * XTS + bt] = tile[nn][bt];
        }
    } else {
        int tsk = (bid - TRB) * 256 + tid;
        wtask(tsk, wsF, Wg, a_src, a_dst, bg, Wc);
    }
}

// D2: bucket scatter (ushort src indices)
__global__ __launch_bounds__(256) void k_scat(
    const int* __restrict__ ei, int* __restrict__ cur,
    unsigned short* __restrict__ bkt)
{
    int e = blockIdx.x * 256 + threadIdx.x;
    if (e < EE) {
        int s = ei[e], d = ei[EE + e];
        int pos = atomicAdd(&cur[d], 1);
        if (pos < CAP) bkt[d * CAP + pos] = (unsigned short)s;
    }
}

// D3: seg-softmax-aggregate (shift-invariant, no max) + conv + head linear.
// 1 wave per node; group g of 8 lanes handles bt {3g,3g+1,3g+2}.
// Lane gl owns bucket slots [8gl, 8gl+8) = one uint4 (slot order irrelevant).
__global__ __launch_bounds__(256) void k_segfinal(
    const int* __restrict__ cur, const unsigned short* __restrict__ bkt,
    const float* __restrict__ wsF,
    const float* __restrict__ bc, const float* __restrict__ Wh,
    const float* __restrict__ bh, float* __restrict__ out)
{
    int tid = threadIdx.x;
    int u = tid >> 6, ul = tid & 63, g = ul >> 3, gl = ul & 7;
    int node = blockIdx.x * NPB + u;
    int bt0 = 3 * g;

    __shared__ float sS[NPB][NBT][NHEAD];
    __shared__ float sz[NPB][BB][NCCH];

    const float* xT = wsF + OFF_XT;

    // parallel, independent loads: count + full bucket row (no dependency)
    int cnt = cur[node];
    uint4 raw = ((const uint4*)(bkt + node * CAP))[gl];
    if (cnt > CAP) cnt = CAP;

    int idxr[8];
    idxr[0] = raw.x & 0xFFFF;  idxr[1] = raw.x >> 16;
    idxr[2] = raw.y & 0xFFFF;  idxr[3] = raw.y >> 16;
    idxr[4] = raw.z & 0xFFFF;  idxr[5] = raw.z >> 16;
    idxr[6] = raw.w & 0xFFFF;  idxr[7] = raw.w >> 16;
#pragma unroll
    for (int i = 0; i < 8; ++i) idxr[i] = min(idxr[i], NN - 1);  // clamp poison

    int slot0 = gl * 8;
    float msk[8];
#pragma unroll
    for (int i = 0; i < 8; ++i) msk[i] = (slot0 + i < cnt) ? 1.f : 0.f;

    // gather 3 bt x-values per slot (12 contiguous bytes), all issued up-front
    float xsr[3][8];
#pragma unroll
    for (int i = 0; i < 8; ++i) {
        const float* r = xT + idxr[i] * XTS + bt0;
        xsr[0][i] = r[0]; xsr[1][i] = r[1]; xsr[2][i] = r[2];
    }
    float xdt[3];
    {
        const float* r = xT + node * XTS + bt0;
        xdt[0] = r[0]; xdt[1] = r[1]; xdt[2] = r[2];
    }

    float cc[4], qq[4];
#pragma unroll
    for (int h = 0; h < 4; ++h) { cc[h] = wsF[OFF_CS + h]; qq[h] = wsF[OFF_CD + h]; }

#pragma unroll
    for (int t = 0; t < 3; ++t) {
#pragma unroll
        for (int h = 0; h < 4; ++h) {
            float dh = qq[h] * xdt[t];
            float a = 0.f, b = 0.f;
#pragma unroll
            for (int i = 0; i < 8; ++i) {
                float xs = xsr[t][i];
                float w = __expf(lrelu(cc[h] * xs + dh)) * msk[i];
                a += w; b += w * xs;
            }
            a += __shfl_xor(a, 1); a += __shfl_xor(a, 2); a += __shfl_xor(a, 4);
            b += __shfl_xor(b, 1); b += __shfl_xor(b, 2); b += __shfl_xor(b, 4);
            if (gl == 0) sS[u][bt0 + t][h] = b / (a + 1e-16f);
        }
    }
    __syncthreads();

    // ---- temporal conv + relu + mean, per output channel o = ul ----
    int o = ul;
    float wcw[NHEAD][KW];
#pragma unroll
    for (int hd = 0; hd < NHEAD; ++hd)
#pragma unroll
        for (int k = 0; k < KW; ++k)
            wcw[hd][k] = wsF[OFF_WCW + o * (NHEAD * KW) + hd * KW + k];
    float cbk[KW];
#pragma unroll
    for (int k = 0; k < KW; ++k) cbk[k] = wsF[OFF_CB + o * KW + k];
    float bco = bc[o];
#pragma unroll
    for (int b = 0; b < BB; ++b) {
        float acc = 0.f;
#pragma unroll
        for (int t = 0; t < TSS; ++t) {
            float zt = bco;
#pragma unroll
            for (int k = 0; k < KW; ++k) {
                int tau = t + k - 1;
                if (tau >= 0 && tau < TSS) {
                    zt += cbk[k];
#pragma unroll
                    for (int hd = 0; hd < NHEAD; ++hd)
                        zt += sS[u][b * TSS + tau][hd] * wcw[hd][k];
                }
            }
            acc += fmaxf(zt, 0.f);
        }
        sz[u][b][o] = acc * (1.f / 12.f);
    }
    __syncthreads();

    if (o < NHOR) {
#pragma unroll
        for (int b = 0; b < BB; ++b) {
            float y = bh[o];
#pragma unroll
            for (int c = 0; c < NCCH; ++c) y += sz[u][b][c] * Wh[o * NCCH + c];
            out[(b * NHOR + o) * NN + node] = y;
        }
    }
}

extern "C" void kernel_launch(void* const* d_in, const int* in_sizes, int n_in,
                              void* d_out, int out_size, void* d_ws, size_t ws_size,
                              hipStream_t stream) {
    const float* x     = (const float*)d_in[0];
    const int*   ei    = (const int*)d_in[1];
    const float* Wg    = (const float*)d_in[2];
    const float* a_src = (const float*)d_in[3];
    const float* a_dst = (const float*)d_in[4];
    const float* bg    = (const float*)d_in[5];
    const float* Wc    = (const float*)d_in[6];
    const float* bc    = (const float*)d_in[7];
    const float* Wh    = (const float*)d_in[8];
    const float* bh    = (const float*)d_in[9];
    float* out = (float*)d_out;
    int*   wsI = (int*)d_ws;
    float* wsF = (float*)d_ws;
    unsigned short* bkt = (unsigned short*)(wsI + OFF_BKT);

    hipLaunchKernelGGL(k_pre, dim3(TRB + WTB), dim3(256), 0, stream,
                       x, wsF, wsI + OFF_CUR, Wg, a_src, a_dst, bg, Wc);
    hipLaunchKernelGGL(k_scat, dim3((EE + 255) / 256), dim3(256), 0, stream,
                       ei, wsI + OFF_CUR, bkt);
    hipLaunchKernelGGL(k_segfinal, dim3(NN / NPB), dim3(256), 0, stream,
                       wsI + OFF_CUR, bkt, wsF, bc, Wh, bh, out);
}